// Round 11
// baseline (317.132 us; speedup 1.0000x reference)
//
#include <hip/hip_runtime.h>

#define N_USER   100000
#define N_ITEM   150000
#define N_NODES  250000
#define N_HID    64
#define E_UI     1000000
#define E_S      1000000
#define N_TOT    (N_NODES + N_USER)      // 350000
#define E_TOT    (E_UI + E_S)            // 2000000

#define BR     64                         // rows per block (spmm)
#define CH     1024                       // edges per binning chunk (20KB LDS)
#define RPB    1024                       // rows per coarse bucket
#define RPB_SH 10
#define NBKT   ((N_TOT + RPB - 1) / RPB)  // 342
#define NBKTP  512                        // padded bucket-array size
#define BSTR   12288                      // fixed pairsA stride per bucket
#define ASTR   72                         // agg LDS row stride (shorts, 144B)

typedef unsigned long long ull;
typedef __attribute__((ext_vector_type(8))) short short8v;   // 8 bf16 (4 VGPR)
typedef __attribute__((ext_vector_type(4))) float f32x4;

__device__ __forceinline__ unsigned short f_to_bf(float f) {
    unsigned u = __float_as_uint(f);
    u += 0x7FFF + ((u >> 16) & 1);
    return (unsigned short)(u >> 16);
}
__device__ __forceinline__ float bf_to_f(unsigned short s) {
    return __uint_as_float((unsigned)s << 16);
}
__device__ __forceinline__ unsigned pack_bf2(float a, float b) {
    return (unsigned)f_to_bf(a) | ((unsigned)f_to_bf(b) << 16);
}

// ===========================================================================
// prepass: bf16 cast of concat(user,item) -> embBf[250K][64]  (LDS-free)
// ===========================================================================
__global__ __launch_bounds__(256) void embcast(const float* __restrict__ u,
                                               const float* __restrict__ it,
                                               unsigned short* __restrict__ embBf) {
    int i = blockIdx.x * 256 + threadIdx.x;
    const int n8 = N_NODES * N_HID / 8;
    if (i >= n8) return;
    size_t base = (size_t)i * 8;
    const size_t nu = (size_t)N_USER * N_HID;
    const float* src = (base < nu) ? u + base : it + (base - nu);
    float4 a = *(const float4*)src;
    float4 b = *(const float4*)(src + 4);
    uint4 o;
    o.x = pack_bf2(a.x, a.y); o.y = pack_bf2(a.z, a.w);
    o.z = pack_bf2(b.x, b.y); o.w = pack_bf2(b.z, b.w);
    *(uint4*)&embBf[base] = o;
}

// ===========================================================================
// seed fixed-stride bucket cursors
// ===========================================================================
__global__ __launch_bounds__(512) void seedk(int* __restrict__ bucketCur) {
    bucketCur[threadIdx.x] = (int)threadIdx.x * BSTR;
}

// ===========================================================================
// binning: LDS sort by coarse bucket into fixed-stride pairsA + fused row hist
//   entry = v<<32 | rLow<<19 | c ;  CH=1024 -> 20KB LDS -> 7 blocks/CU
// ===========================================================================
__global__ __launch_bounds__(256) void bin_pass1(const int* __restrict__ ui_rows,
                                                 const int* __restrict__ ui_cols,
                                                 const float* __restrict__ ui_vals,
                                                 const int* __restrict__ s_rows,
                                                 const int* __restrict__ s_cols,
                                                 const float* __restrict__ s_vals,
                                                 int* __restrict__ bucketCur,
                                                 int* __restrict__ rowHist,
                                                 ull* __restrict__ pairsA) {
    __shared__ ull            staged[CH];
    __shared__ unsigned short bkt[CH];
    __shared__ unsigned short ord[CH];
    __shared__ int hist[NBKTP];
    __shared__ int lstart[NBKTP];
    __shared__ int cnt2[NBKTP];
    __shared__ int baseg[NBKTP];
    const int t = threadIdx.x;
    hist[t] = 0; hist[t + 256] = 0;
    cnt2[t] = 0; cnt2[t + 256] = 0;
    __syncthreads();

    const int e0 = blockIdx.x * CH;
    const int n  = min(CH, E_TOT - e0);

    for (int i = t; i < n; i += 256) {
        int g = e0 + i, r, c; float v;
        if (g < E_UI) { r = ui_rows[g];            c = ui_cols[g];            v = ui_vals[g]; }
        else          { int k = g - E_UI;
                        r = N_NODES + s_rows[k];   c = N_NODES + s_cols[k];   v = s_vals[k]; }
        int b = r >> RPB_SH;
        staged[i] = ((ull)__float_as_uint(v) << 32) |
                    ((ull)(unsigned)(r & (RPB - 1)) << 19) | (unsigned)c;
        bkt[i] = (unsigned short)b;
        atomicAdd(&hist[b], 1);
        atomicAdd(&rowHist[r], 1);                // fused per-row histogram
    }
    __syncthreads();

    int v0 = hist[t], v1 = hist[t + 256];
    lstart[t] = v0; lstart[t + 256] = v1;
    __syncthreads();
    for (int off = 1; off < NBKTP; off <<= 1) {
        int a = (t >= off) ? lstart[t - off] : 0;
        int b = (t + 256 >= off) ? lstart[t + 256 - off] : 0;
        __syncthreads();
        lstart[t] += a; lstart[t + 256] += b;
        __syncthreads();
    }
    int ex0 = lstart[t] - v0, ex1 = lstart[t + 256] - v1;
    __syncthreads();
    lstart[t] = ex0; lstart[t + 256] = ex1;
    if (v0 > 0) baseg[t] = atomicAdd(&bucketCur[t], v0);
    if (v1 > 0) baseg[t + 256] = atomicAdd(&bucketCur[t + 256], v1);
    __syncthreads();

    for (int i = t; i < n; i += 256) {
        int b = bkt[i];
        int l = atomicAdd(&cnt2[b], 1);
        ord[lstart[b] + l] = (unsigned short)i;
    }
    __syncthreads();

    for (int k = t; k < n; k += 256) {
        int i = ord[k];
        int b = bkt[i];
        pairsA[(size_t)baseg[b] + (k - lstart[b])] = staged[i];
    }
}

// ===========================================================================
// scan over rowStart counts, length n (= N_TOT+1; slot N_TOT holds 0 so the
// final exclusive value is the padded/unpadded total). pad: round counts to 8.
// ===========================================================================
__global__ __launch_bounds__(256) void scan_block512(int* __restrict__ data,
                                                     int* __restrict__ blockSums,
                                                     int n, int pad) {
    __shared__ int sm[512];
    int t = threadIdx.x;
    int base = blockIdx.x * 512;
    int i0 = base + t, i1 = base + t + 256;
    int v0 = (i0 < n) ? data[i0] : 0;
    int v1 = (i1 < n) ? data[i1] : 0;
    if (pad) { v0 = (v0 + 7) & ~7; v1 = (v1 + 7) & ~7; }
    sm[t] = v0; sm[t + 256] = v1;
    __syncthreads();
    for (int off = 1; off < 512; off <<= 1) {
        int a = (t >= off) ? sm[t - off] : 0;
        int b = (t + 256 >= off) ? sm[t + 256 - off] : 0;
        __syncthreads();
        sm[t] += a; sm[t + 256] += b;
        __syncthreads();
    }
    if (i0 < n) data[i0] = sm[t] - v0;
    if (i1 < n) data[i1] = sm[t + 256] - v1;
    if (t == 255) blockSums[blockIdx.x] = sm[511];
}

__global__ __launch_bounds__(1024) void scan_sums(int* __restrict__ blockSums, int nb) {
    __shared__ int sm[1024];
    int v = (threadIdx.x < nb) ? blockSums[threadIdx.x] : 0;
    sm[threadIdx.x] = v;
    __syncthreads();
    for (int off = 1; off < 1024; off <<= 1) {
        int t = (threadIdx.x >= off) ? sm[threadIdx.x - off] : 0;
        __syncthreads();
        sm[threadIdx.x] += t;
        __syncthreads();
    }
    if (threadIdx.x < nb) blockSums[threadIdx.x] = sm[threadIdx.x] - v;
}

__global__ __launch_bounds__(256) void scan_add512(int* __restrict__ data,
                                                   const int* __restrict__ blockSums,
                                                   int n) {
    int base = blockIdx.x * 512;
    int s = blockSums[blockIdx.x];
#pragma unroll
    for (int k = 0; k < 2; ++k) {
        int i = base + threadIdx.x + k * 256;
        if (i < n) data[i] += s;
    }
}

// ===========================================================================
// fine scatter: one block per bucket, LDS row cursors; L2-local writes.
// padfill: zero-fill each row's pad slots (slots between end-of-edges and
// next row's padded start) so spmm can run mask-free.
// ===========================================================================
__global__ __launch_bounds__(512) void fine_pass2(const ull* __restrict__ pairsA,
                                                  const int* __restrict__ rowStart,
                                                  const int* __restrict__ bucketCur,
                                                  ull* __restrict__ pairs,
                                                  int padfill) {
    __shared__ int cur[RPB];
    const int b = blockIdx.x, t = threadIdx.x;
    const int r0 = b * RPB;
    const int nr = min(RPB, N_TOT - r0);
    for (int i = t; i < nr; i += 512) cur[i] = rowStart[r0 + i];
    __syncthreads();
    const int base = b * BSTR;
    const int cnt  = bucketCur[b] - base;
    for (int j = t; j < cnt; j += 512) {
        ull e = pairsA[base + j];
        int rLow = (int)((e >> 19) & (RPB - 1));
        int pos = atomicAdd(&cur[rLow], 1);
        pairs[pos] = (e & 0xFFFFFFFF00000000ull) | (e & 0x7FFFFull);
    }
    if (padfill) {
        __syncthreads();
        for (int i = t; i < nr; i += 512) {
            int end = rowStart[r0 + i + 1];
            for (int j = cur[i]; j < end; ++j) pairs[j] = 0;   // v=0, c=0
        }
    }
}

// ===========================================================================
// spmm_m: quarter-wave gather (bf16 sources) + MFMA W-apply epilogue.
//   PADDED: rows are 8-aligned with zero-val pad entries -> mask-free loop.
//   LAYER 1: gather embBf; tmp12 = bf16(emb+n1); B2 = bf16(lv1)
//   LAYER 2: gather B2;    out = f32(tmp12) + n2
// ===========================================================================
template <int LAYER, bool PADDED>
__global__ __launch_bounds__(256) void spmm_m(const ull* __restrict__ pairs,
                                              const int* __restrict__ rowStart,
                                              const unsigned short* __restrict__ embBf,
                                              const unsigned short* __restrict__ B2in,
                                              unsigned short* __restrict__ B2out,
                                              const unsigned short* __restrict__ tmp12in,
                                              unsigned short* __restrict__ tmp12out,
                                              const float* __restrict__ Wui,
                                              const float* __restrict__ Wsoc,
                                              float* __restrict__ out_ui,
                                              float* __restrict__ out_s,
                                              int uiBlocks) {
    __shared__ unsigned short Wb[N_HID][ASTR];        // Wb[c][r] = bf16(W[r][c])
    __shared__ unsigned short agg[4][16][ASTR];
    const int tid = threadIdx.x;
    const bool isUI = (int)blockIdx.x < uiBlocks;
    const int bl    = isUI ? blockIdx.x : blockIdx.x - uiBlocks;
    const int rbeg  = isUI ? bl * BR : N_NODES + bl * BR;
    const int rlim  = isUI ? min(BR, N_NODES - bl * BR) : min(BR, N_USER - bl * BR);

    const float* W = isUI ? Wui : Wsoc;
    for (int idx = tid; idx < N_HID * N_HID; idx += 256) {
        int r = idx >> 6, c = idx & 63;
        Wb[c][r] = f_to_bf(W[idx]);
    }
    __syncthreads();

    const int w = tid >> 6;
    if (w * 16 >= rlim) return;             // rlim is always a multiple of 16
    const int s = tid & 15;
    const int g = (tid >> 4) & 3;

    short8v bfrag[4][2];
#pragma unroll
    for (int nt = 0; nt < 4; ++nt)
#pragma unroll
        for (int kt = 0; kt < 2; ++kt)
            bfrag[nt][kt] = *(const short8v*)&Wb[nt * 16 + s][kt * 32 + g * 8];

    const unsigned short* gsrc = (LAYER == 1) ? embBf : B2in;

    int sB[4], eB[4];
#pragma unroll
    for (int i = 0; i < 4; ++i) {
        int r = rbeg + w * 16 + i * 4 + g;
        sB[i] = rowStart[r];
        eB[i] = rowStart[r + 1];
    }

    for (int i = 0; i < 4; ++i) {
        float4 acc = make_float4(0.f, 0.f, 0.f, 0.f);
        if (PADDED) {
            for (int j = sB[i]; j < eB[i]; j += 8) {   // mask-free: pads have v=0
                ull p[8];
#pragma unroll
                for (int k = 0; k < 8; ++k) p[k] = pairs[j + k];
                ushort4 raw[8];
#pragma unroll
                for (int k = 0; k < 8; ++k) {
                    unsigned c = (unsigned)p[k] & 0x7FFFFu;
                    if (LAYER == 1 && c >= N_NODES) c -= N_NODES;
                    raw[k] = *(const ushort4*)(gsrc + (size_t)c * N_HID + s * 4);
                }
#pragma unroll
                for (int k = 0; k < 8; ++k) {
                    float v = __uint_as_float((unsigned)(p[k] >> 32));
                    acc.x = fmaf(v, bf_to_f(raw[k].x), acc.x);
                    acc.y = fmaf(v, bf_to_f(raw[k].y), acc.y);
                    acc.z = fmaf(v, bf_to_f(raw[k].z), acc.z);
                    acc.w = fmaf(v, bf_to_f(raw[k].w), acc.w);
                }
            }
        } else {
            int e0 = eB[i];
            for (int j = sB[i]; j < e0; j += 8) {
                int last = e0 - 1;
                ull p[8];
#pragma unroll
                for (int k = 0; k < 8; ++k) p[k] = pairs[min(j + k, last)];
                ushort4 raw[8];
#pragma unroll
                for (int k = 0; k < 8; ++k) {
                    unsigned c = (unsigned)p[k] & 0x7FFFFu;
                    if (LAYER == 1 && c >= N_NODES) c -= N_NODES;
                    raw[k] = *(const ushort4*)(gsrc + (size_t)c * N_HID + s * 4);
                }
#pragma unroll
                for (int k = 0; k < 8; ++k) {
                    float v = (j + k < e0) ? __uint_as_float((unsigned)(p[k] >> 32)) : 0.f;
                    acc.x = fmaf(v, bf_to_f(raw[k].x), acc.x);
                    acc.y = fmaf(v, bf_to_f(raw[k].y), acc.y);
                    acc.z = fmaf(v, bf_to_f(raw[k].z), acc.z);
                    acc.w = fmaf(v, bf_to_f(raw[k].w), acc.w);
                }
            }
        }
        uint2 pk;
        pk.x = pack_bf2(acc.x, acc.y);
        pk.y = pack_bf2(acc.z, acc.w);
        *(uint2*)&agg[w][i * 4 + g][s * 4] = pk;
    }
    asm volatile("s_waitcnt lgkmcnt(0)" ::: "memory");
    __builtin_amdgcn_sched_barrier(0);

    // ---- MFMA: z(16x64) = agg(16x64) @ W(64x64) ----
    short8v a0 = *(const short8v*)&agg[w][s][g * 8];
    short8v a1 = *(const short8v*)&agg[w][s][32 + g * 8];
    f32x4 c[4];
    const f32x4 zero4 = {0.f, 0.f, 0.f, 0.f};
#pragma unroll
    for (int nt = 0; nt < 4; ++nt) {
        c[nt] = __builtin_amdgcn_mfma_f32_16x16x32_bf16(a0, bfrag[nt][0], zero4, 0, 0, 0);
        c[nt] = __builtin_amdgcn_mfma_f32_16x16x32_bf16(a1, bfrag[nt][1], c[nt], 0, 0, 0);
    }

    // ---- leaky + row l2norm (C/D: col = nt*16+s, row = g*4+r) ----
    float lv[4][4];
    float ss[4] = {0.f, 0.f, 0.f, 0.f};
#pragma unroll
    for (int nt = 0; nt < 4; ++nt)
#pragma unroll
        for (int r = 0; r < 4; ++r) {
            float z = c[nt][r];
            float l = (z >= 0.f) ? z : 0.5f * z;
            lv[nt][r] = l;
            ss[r] = fmaf(l, l, ss[r]);
        }
#pragma unroll
    for (int r = 0; r < 4; ++r) {
        float t = ss[r];
        t += __shfl_xor(t, 1, 64);
        t += __shfl_xor(t, 2, 64);
        t += __shfl_xor(t, 4, 64);
        t += __shfl_xor(t, 8, 64);
        ss[r] = 1.f / fmaxf(sqrtf(t), 1e-12f);
    }

    // ---- outputs ----
#pragma unroll
    for (int r = 0; r < 4; ++r) {
        int R = rbeg + w * 16 + g * 4 + r;
        if (LAYER == 1) {
            size_t eRow = isUI ? (size_t)R : (size_t)(R - N_NODES);
#pragma unroll
            for (int nt = 0; nt < 4; ++nt) {
                int col = nt * 16 + s;
                float eb = bf_to_f(embBf[eRow * N_HID + col]);
                tmp12out[(size_t)R * N_HID + col] = f_to_bf(fmaf(lv[nt][r], ss[r], eb));
                B2out[(size_t)R * N_HID + col]    = f_to_bf(lv[nt][r]);
            }
        } else {
            float* op = isUI ? out_ui + (size_t)R * N_HID
                             : out_s  + (size_t)(R - N_NODES) * N_HID;
#pragma unroll
            for (int nt = 0; nt < 4; ++nt) {
                int col = nt * 16 + s;
                float tb = bf_to_f(tmp12in[(size_t)R * N_HID + col]);
                op[col] = fmaf(lv[nt][r], ss[r], tb);
            }
        }
    }
}

// ===========================================================================
// Atomic fallback (only if ws too small for the sorted path)
// ===========================================================================
__global__ __launch_bounds__(256) void init_concat(const float* __restrict__ u,
                                                   const float* __restrict__ it,
                                                   float* __restrict__ A,
                                                   float* __restrict__ out) {
    int i = blockIdx.x * 256 + threadIdx.x;
    const int nu4 = N_USER * N_HID / 4;
    const int nt4 = N_NODES * N_HID / 4;
    if (i >= nt4) return;
    float4 v = (i < nu4) ? ((const float4*)u)[i] : ((const float4*)it)[i - nu4];
    ((float4*)A)[i]   = v;
    ((float4*)out)[i] = v;
}

__global__ __launch_bounds__(256) void copy2(const float* __restrict__ src,
                                             float* __restrict__ d0,
                                             float* __restrict__ d1, int n4) {
    int i = blockIdx.x * 256 + threadIdx.x;
    if (i >= n4) return;
    float4 v = ((const float4*)src)[i];
    ((float4*)d0)[i] = v;
    ((float4*)d1)[i] = v;
}

__global__ __launch_bounds__(256) void gemm64(const float* __restrict__ X,
                                              const float* __restrict__ W,
                                              float* __restrict__ Y, int nrows) {
    __shared__ float Ws[N_HID * N_HID];
    int tid = threadIdx.x;
#pragma unroll
    for (int c = 0; c < 16; ++c) Ws[c * 256 + tid] = W[c * 256 + tid];
    __syncthreads();
    int row = blockIdx.x * 256 + tid;
    if (row >= nrows) return;
    float x[N_HID];
    const float4* xr = (const float4*)(X + (size_t)row * N_HID);
#pragma unroll
    for (int c = 0; c < 16; ++c) {
        float4 v = xr[c];
        x[4*c+0] = v.x; x[4*c+1] = v.y; x[4*c+2] = v.z; x[4*c+3] = v.w;
    }
    float4* y4 = (float4*)(Y + (size_t)row * N_HID);
    for (int jc = 0; jc < 16; ++jc) {
        float4 a = make_float4(0.f,0.f,0.f,0.f);
#pragma unroll
        for (int k = 0; k < N_HID; ++k) {
            float4 wv = *((const float4*)&Ws[k * N_HID + jc * 4]);
            a.x += x[k]*wv.x; a.y += x[k]*wv.y; a.z += x[k]*wv.z; a.w += x[k]*wv.w;
        }
        y4[jc] = a;
    }
}

__global__ __launch_bounds__(256) void spmm_scatter(const int* __restrict__ rows,
                                                    const int* __restrict__ cols,
                                                    const float* __restrict__ vals,
                                                    const float* __restrict__ X,
                                                    float* __restrict__ Y, int nedges) {
    long long t = (long long)blockIdx.x * 256 + threadIdx.x;
    int e = (int)(t >> 6);
    int h = (int)(t & 63);
    if (e >= nedges) return;
    atomicAdd(&Y[rows[e] * N_HID + h], vals[e] * X[cols[e] * N_HID + h]);
}

__global__ __launch_bounds__(256) void leaky_norm_acc(float* __restrict__ Y,
                                                      float* __restrict__ out, int nrows) {
    int row = blockIdx.x * 4 + (threadIdx.x >> 6);
    int h   = threadIdx.x & 63;
    if (row >= nrows) return;
    int idx = row * N_HID + h;
    float v = Y[idx];
    v = (v >= 0.f) ? v : 0.5f * v;
    Y[idx] = v;
    float s = v * v;
#pragma unroll
    for (int off = 32; off > 0; off >>= 1) s += __shfl_xor(s, off, 64);
    out[idx] += v / fmaxf(sqrtf(s), 1e-12f);
}

// ===========================================================================
extern "C" void kernel_launch(void* const* d_in, const int* in_sizes, int n_in,
                              void* d_out, int out_size, void* d_ws, size_t ws_size,
                              hipStream_t stream) {
    const float* user_emb = (const float*)d_in[0];
    const float* item_emb = (const float*)d_in[1];
    const float* ui_w     = (const float*)d_in[2];
    const float* s_w      = (const float*)d_in[3];
    const int*   ui_rows  = (const int*)d_in[4];
    const int*   ui_cols  = (const int*)d_in[5];
    const float* ui_vals  = (const float*)d_in[6];
    const int*   s_rows   = (const int*)d_in[7];
    const int*   s_cols   = (const int*)d_in[8];
    const float* s_vals   = (const float*)d_in[9];

    float* out_ui = (float*)d_out;
    float* out_s  = (float*)d_out + (size_t)N_NODES * N_HID;

    const size_t szUI  = (size_t)N_NODES * N_HID * sizeof(float);     // 64.0 MB
    const size_t szEB  = (size_t)N_NODES * N_HID * sizeof(short);     // 32.0 MB
    const size_t szBF  = (size_t)N_TOT   * N_HID * sizeof(short);     // 44.8 MB
    const size_t rsPad = 1400832;                                     // (N_TOT+1)*4 pad

    const int uiBlocks = (N_NODES + BR - 1) / BR;    // 3907
    const int sBlocks  = (N_USER  + BR - 1) / BR;    // 1563
    const int nbScan   = (N_TOT + 1 + 511) / 512;    // 684
    const int nbBin    = (E_TOT + CH - 1) / CH;      // 1954
    const int nbEC     = (N_NODES * N_HID / 8 + 255) / 256;

    // worst-case padded pairs: every row pads +7
    const size_t pairsCapPad = ((size_t)E_TOT + 7ull * N_TOT) * 8;    // 35.6 MB
    const size_t pairsCapStd = (size_t)E_TOT * 8;                     // 16.0 MB

    const size_t needPad = szEB + 2 * szBF + pairsCapPad + rsPad + 8192 + 8192;
    const size_t needStd = szEB + 2 * szBF + pairsCapStd + rsPad + 8192 + 8192;

    if (ws_size >= needStd) {
        const bool padded = (ws_size >= needPad);
        const size_t pairsCap = padded ? pairsCapPad : pairsCapStd;

        unsigned short* embBf = (unsigned short*)d_ws;
        unsigned short* B2    = (unsigned short*)((char*)d_ws + szEB);
        unsigned short* tmp12 = (unsigned short*)((char*)d_ws + szEB + szBF);
        char* p = (char*)d_ws + szEB + 2 * szBF;
        ull* pairs     = (ull*)p;            p += pairsCap;
        int* rowStart  = (int*)p;            p += rsPad;
        int* blockSums = (int*)p;            p += 8192;
        int* bucketCur = (int*)p;
        ull* pairsA    = (ull*)tmp12;        // staging aliases tmp12 (dead until L1 epi)

        // ---- prepass + sort ----
        embcast<<<nbEC, 256, 0, stream>>>(user_emb, item_emb, embBf);
        hipMemsetAsync(rowStart, 0, (size_t)(N_TOT + 1) * 4, stream);
        seedk<<<1, 512, 0, stream>>>(bucketCur);
        bin_pass1<<<nbBin, 256, 0, stream>>>(ui_rows, ui_cols, ui_vals,
                                             s_rows, s_cols, s_vals,
                                             bucketCur, rowStart, pairsA);
        scan_block512<<<nbScan, 256, 0, stream>>>(rowStart, blockSums,
                                                  N_TOT + 1, padded ? 1 : 0);
        scan_sums<<<1, 1024, 0, stream>>>(blockSums, nbScan);
        scan_add512<<<nbScan, 256, 0, stream>>>(rowStart, blockSums, N_TOT + 1);
        fine_pass2<<<NBKT, 512, 0, stream>>>(pairsA, rowStart, bucketCur, pairs,
                                             padded ? 1 : 0);

        // ---- 2 fused spmm dispatches (MFMA epilogue) ----
        const int grid = uiBlocks + sBlocks;
        const float* Wui2 = ui_w + N_HID * N_HID;
        const float* Ws2  = s_w  + N_HID * N_HID;
        if (padded) {
            spmm_m<1, true><<<grid, 256, 0, stream>>>(pairs, rowStart, embBf,
                                                      nullptr, B2, nullptr, tmp12,
                                                      ui_w, s_w, out_ui, out_s, uiBlocks);
            spmm_m<2, true><<<grid, 256, 0, stream>>>(pairs, rowStart, embBf,
                                                      B2, nullptr, tmp12, nullptr,
                                                      Wui2, Ws2, out_ui, out_s, uiBlocks);
        } else {
            spmm_m<1, false><<<grid, 256, 0, stream>>>(pairs, rowStart, embBf,
                                                       nullptr, B2, nullptr, tmp12,
                                                       ui_w, s_w, out_ui, out_s, uiBlocks);
            spmm_m<2, false><<<grid, 256, 0, stream>>>(pairs, rowStart, embBf,
                                                       B2, nullptr, tmp12, nullptr,
                                                       Wui2, Ws2, out_ui, out_s, uiBlocks);
        }
        return;
    }

    // ------------------- fallback: atomic path -------------------
    float* A = (float*)d_ws;
    float* B = (float*)((char*)d_ws + szUI);
    init_concat<<<(N_NODES * N_HID / 4 + 255) / 256, 256, 0, stream>>>(
        user_emb, item_emb, A, out_ui);
    for (int l = 0; l < 2; ++l) {
        gemm64<<<(N_NODES + 255) / 256, 256, 0, stream>>>(
            A, ui_w + l * N_HID * N_HID, B, N_NODES);
        hipMemsetAsync(A, 0, szUI, stream);
        spmm_scatter<<<(int)(((long long)E_UI * 64) / 256), 256, 0, stream>>>(
            ui_rows, ui_cols, ui_vals, B, A, E_UI);
        leaky_norm_acc<<<(N_NODES + 3) / 4, 256, 0, stream>>>(A, out_ui, N_NODES);
    }
    copy2<<<(N_USER * N_HID / 4 + 255) / 256, 256, 0, stream>>>(
        user_emb, A, out_s, N_USER * N_HID / 4);
    const size_t sBytes = (size_t)N_USER * N_HID * sizeof(float);
    for (int l = 0; l < 2; ++l) {
        gemm64<<<(N_USER + 255) / 256, 256, 0, stream>>>(
            A, s_w + l * N_HID * N_HID, B, N_USER);
        hipMemsetAsync(A, 0, sBytes, stream);
        spmm_scatter<<<(int)(((long long)E_S * 64) / 256), 256, 0, stream>>>(
            s_rows, s_cols, s_vals, B, A, E_S);
        leaky_norm_acc<<<(N_USER + 3) / 4, 256, 0, stream>>>(A, out_s, N_USER);
    }
}

// Round 12
// 309.645 us; speedup vs baseline: 1.0242x; 1.0242x over previous
//
#include <hip/hip_runtime.h>

#define N_USER   100000
#define N_ITEM   150000
#define N_NODES  250000
#define N_HID    64
#define E_UI     1000000
#define E_S      1000000
#define N_TOT    (N_NODES + N_USER)      // 350000
#define E_TOT    (E_UI + E_S)            // 2000000

#define BR     64                         // rows per block (spmm)
#define CH     8192                       // edges per binning chunk
#define NBBIN  ((E_TOT + CH - 1) / CH)    // 245
#define RPB    1024                       // rows per coarse bucket
#define RPB_SH 10
#define NBKT   ((N_TOT + RPB - 1) / RPB)  // 342
#define NBKTP  512                        // padded bucket-array size
#define LSTR   344                        // lstartAll row stride (ints)
#define ASTR   72                         // agg LDS row stride (shorts, 144B)

typedef unsigned long long ull;
typedef __attribute__((ext_vector_type(8))) short short8v;   // 8 bf16 (4 VGPR)
typedef __attribute__((ext_vector_type(4))) float f32x4;

__device__ __forceinline__ unsigned short f_to_bf(float f) {
    unsigned u = __float_as_uint(f);
    u += 0x7FFF + ((u >> 16) & 1);
    return (unsigned short)(u >> 16);
}
__device__ __forceinline__ float bf_to_f(unsigned short s) {
    return __uint_as_float((unsigned)s << 16);
}
__device__ __forceinline__ unsigned pack_bf2(float a, float b) {
    return (unsigned)f_to_bf(a) | ((unsigned)f_to_bf(b) << 16);
}

// ===========================================================================
// prepass: bf16 cast of concat(user,item) -> embBf[250K][64]  (LDS-free)
// ===========================================================================
__global__ __launch_bounds__(256) void embcast(const float* __restrict__ u,
                                               const float* __restrict__ it,
                                               unsigned short* __restrict__ embBf) {
    int i = blockIdx.x * 256 + threadIdx.x;
    const int n8 = N_NODES * N_HID / 8;
    if (i >= n8) return;
    size_t base = (size_t)i * 8;
    const size_t nu = (size_t)N_USER * N_HID;
    const float* src = (base < nu) ? u + base : it + (base - nu);
    float4 a = *(const float4*)src;
    float4 b = *(const float4*)(src + 4);
    uint4 o;
    o.x = pack_bf2(a.x, a.y); o.y = pack_bf2(a.z, a.w);
    o.z = pack_bf2(b.x, b.y); o.w = pack_bf2(b.z, b.w);
    *(uint4*)&embBf[base] = o;
}

// ===========================================================================
// bin_local: per-block private bucket-grouping (NO global cursors).
//   phase 1: histogram (LDS) + fused rowHist atomics
//   scan:    512-wide exclusive prefix -> lstart; written to lstartAll
//   phase 2: re-read edges (coalesced), place into private region
//            pairsA[blk*CH + lstart[b] + l]  (writes confined to 64KB region)
//   entry = v<<32 | rLow<<19 | c
// ===========================================================================
__global__ __launch_bounds__(512) void bin_local(const int* __restrict__ ui_rows,
                                                 const int* __restrict__ ui_cols,
                                                 const float* __restrict__ ui_vals,
                                                 const int* __restrict__ s_rows,
                                                 const int* __restrict__ s_cols,
                                                 const float* __restrict__ s_vals,
                                                 int* __restrict__ rowHist,
                                                 ull* __restrict__ pairsA,
                                                 int* __restrict__ lstartAll) {
    __shared__ int hist[NBKTP];
    __shared__ int lstart[NBKTP];
    __shared__ int cnt2[NBKTP];
    const int t = threadIdx.x;
    hist[t] = 0; cnt2[t] = 0;
    __syncthreads();

    const int e0 = blockIdx.x * CH;
    const int n  = min(CH, E_TOT - e0);

    // phase 1: histogram
    for (int i = t; i < n; i += 512) {
        int g = e0 + i, r;
        if (g < E_UI) r = ui_rows[g];
        else          r = N_NODES + s_rows[g - E_UI];
        atomicAdd(&hist[r >> RPB_SH], 1);
        atomicAdd(&rowHist[r], 1);
    }
    __syncthreads();

    // 512-wide exclusive scan (1 elem/thread)
    int v = hist[t];
    lstart[t] = v;
    __syncthreads();
    for (int off = 1; off < NBKTP; off <<= 1) {
        int a = (t >= off) ? lstart[t - off] : 0;
        __syncthreads();
        lstart[t] += a;
        __syncthreads();
    }
    int ex = lstart[t] - v;
    __syncthreads();
    lstart[t] = ex;
    if (t <= NBKT) lstartAll[blockIdx.x * LSTR + t] = ex;   // [NBKT] = n
    __syncthreads();

    // phase 2: re-read + place grouped into private region
    for (int i = t; i < n; i += 512) {
        int g = e0 + i, r, c; float val;
        if (g < E_UI) { r = ui_rows[g];            c = ui_cols[g];            val = ui_vals[g]; }
        else          { int k = g - E_UI;
                        r = N_NODES + s_rows[k];   c = N_NODES + s_cols[k];   val = s_vals[k]; }
        int b = r >> RPB_SH;
        ull entry = ((ull)__float_as_uint(val) << 32) |
                    ((ull)(unsigned)(r & (RPB - 1)) << 19) | (unsigned)c;
        int l = atomicAdd(&cnt2[b], 1);
        pairsA[(size_t)blockIdx.x * CH + lstart[b] + l] = entry;
    }
}

// ===========================================================================
// scan over rowStart counts, length n (= N_TOT+1). pad: round counts to 8.
// ===========================================================================
__global__ __launch_bounds__(256) void scan_block512(int* __restrict__ data,
                                                     int* __restrict__ blockSums,
                                                     int n, int pad) {
    __shared__ int sm[512];
    int t = threadIdx.x;
    int base = blockIdx.x * 512;
    int i0 = base + t, i1 = base + t + 256;
    int v0 = (i0 < n) ? data[i0] : 0;
    int v1 = (i1 < n) ? data[i1] : 0;
    if (pad) { v0 = (v0 + 7) & ~7; v1 = (v1 + 7) & ~7; }
    sm[t] = v0; sm[t + 256] = v1;
    __syncthreads();
    for (int off = 1; off < 512; off <<= 1) {
        int a = (t >= off) ? sm[t - off] : 0;
        int b = (t + 256 >= off) ? sm[t + 256 - off] : 0;
        __syncthreads();
        sm[t] += a; sm[t + 256] += b;
        __syncthreads();
    }
    if (i0 < n) data[i0] = sm[t] - v0;
    if (i1 < n) data[i1] = sm[t + 256] - v1;
    if (t == 255) blockSums[blockIdx.x] = sm[511];
}

__global__ __launch_bounds__(1024) void scan_sums(int* __restrict__ blockSums, int nb) {
    __shared__ int sm[1024];
    int v = (threadIdx.x < nb) ? blockSums[threadIdx.x] : 0;
    sm[threadIdx.x] = v;
    __syncthreads();
    for (int off = 1; off < 1024; off <<= 1) {
        int t = (threadIdx.x >= off) ? sm[threadIdx.x - off] : 0;
        __syncthreads();
        sm[threadIdx.x] += t;
        __syncthreads();
    }
    if (threadIdx.x < nb) blockSums[threadIdx.x] = sm[threadIdx.x] - v;
}

__global__ __launch_bounds__(256) void scan_add512(int* __restrict__ data,
                                                   const int* __restrict__ blockSums,
                                                   int n) {
    int base = blockIdx.x * 512;
    int s = blockSums[blockIdx.x];
#pragma unroll
    for (int k = 0; k < 2; ++k) {
        int i = base + threadIdx.x + k * 256;
        if (i < n) data[i] += s;
    }
}

// ===========================================================================
// fine_gather: one block per bucket; pull the bucket's segment from each
// bin_local region (via lstartAll), scatter to exact CSR via LDS cursors.
// Quarter-wave (16 lanes) per segment; L2-local writes; optional pad-fill.
// ===========================================================================
__global__ __launch_bounds__(512) void fine_gather(const ull* __restrict__ pairsA,
                                                   const int* __restrict__ lstartAll,
                                                   const int* __restrict__ rowStart,
                                                   ull* __restrict__ pairs,
                                                   int padfill) {
    __shared__ int cur[RPB];
    const int b = blockIdx.x, t = threadIdx.x;
    const int r0 = b * RPB;
    const int nr = min(RPB, N_TOT - r0);
    for (int i = t; i < nr; i += 512) cur[i] = rowStart[r0 + i];
    __syncthreads();

    const int q    = t >> 4;        // 32 quarters
    const int lane = t & 15;
    for (int blk = q; blk < NBBIN; blk += 32) {
        int s = lstartAll[blk * LSTR + b];
        int e = lstartAll[blk * LSTR + b + 1];
        const ull* src = pairsA + (size_t)blk * CH;
        for (int j = s + lane; j < e; j += 16) {
            ull en = src[j];
            int rLow = (int)((en >> 19) & (RPB - 1));
            int pos = atomicAdd(&cur[rLow], 1);
            pairs[pos] = (en & 0xFFFFFFFF00000000ull) | (en & 0x7FFFFull);
        }
    }
    if (padfill) {
        __syncthreads();
        for (int i = t; i < nr; i += 512) {
            int end = rowStart[r0 + i + 1];
            for (int j = cur[i]; j < end; ++j) pairs[j] = 0;   // v=0, c=0
        }
    }
}

// ===========================================================================
// spmm_m: quarter-wave gather (bf16 sources) + MFMA W-apply epilogue.
//   PADDED: rows are 8-aligned with zero-val pad entries -> mask-free loop.
//   LAYER 1: gather embBf; tmp12 = bf16(emb+n1); B2 = bf16(lv1)
//   LAYER 2: gather B2;    out = f32(tmp12) + n2
// ===========================================================================
template <int LAYER, bool PADDED>
__global__ __launch_bounds__(256) void spmm_m(const ull* __restrict__ pairs,
                                              const int* __restrict__ rowStart,
                                              const unsigned short* __restrict__ embBf,
                                              const unsigned short* __restrict__ B2in,
                                              unsigned short* __restrict__ B2out,
                                              const unsigned short* __restrict__ tmp12in,
                                              unsigned short* __restrict__ tmp12out,
                                              const float* __restrict__ Wui,
                                              const float* __restrict__ Wsoc,
                                              float* __restrict__ out_ui,
                                              float* __restrict__ out_s,
                                              int uiBlocks) {
    __shared__ unsigned short Wb[N_HID][ASTR];        // Wb[c][r] = bf16(W[r][c])
    __shared__ unsigned short agg[4][16][ASTR];
    const int tid = threadIdx.x;
    const bool isUI = (int)blockIdx.x < uiBlocks;
    const int bl    = isUI ? blockIdx.x : blockIdx.x - uiBlocks;
    const int rbeg  = isUI ? bl * BR : N_NODES + bl * BR;
    const int rlim  = isUI ? min(BR, N_NODES - bl * BR) : min(BR, N_USER - bl * BR);

    const float* W = isUI ? Wui : Wsoc;
    for (int idx = tid; idx < N_HID * N_HID; idx += 256) {
        int r = idx >> 6, c = idx & 63;
        Wb[c][r] = f_to_bf(W[idx]);
    }
    __syncthreads();

    const int w = tid >> 6;
    if (w * 16 >= rlim) return;             // rlim is always a multiple of 16
    const int s = tid & 15;
    const int g = (tid >> 4) & 3;

    short8v bfrag[4][2];
#pragma unroll
    for (int nt = 0; nt < 4; ++nt)
#pragma unroll
        for (int kt = 0; kt < 2; ++kt)
            bfrag[nt][kt] = *(const short8v*)&Wb[nt * 16 + s][kt * 32 + g * 8];

    const unsigned short* gsrc = (LAYER == 1) ? embBf : B2in;

    int sB[4], eB[4];
#pragma unroll
    for (int i = 0; i < 4; ++i) {
        int r = rbeg + w * 16 + i * 4 + g;
        sB[i] = rowStart[r];
        eB[i] = rowStart[r + 1];
    }

    for (int i = 0; i < 4; ++i) {
        float4 acc = make_float4(0.f, 0.f, 0.f, 0.f);
        if (PADDED) {
            for (int j = sB[i]; j < eB[i]; j += 8) {   // mask-free: pads have v=0
                ull p[8];
#pragma unroll
                for (int k = 0; k < 8; ++k) p[k] = pairs[j + k];
                ushort4 raw[8];
#pragma unroll
                for (int k = 0; k < 8; ++k) {
                    unsigned c = (unsigned)p[k] & 0x7FFFFu;
                    if (LAYER == 1 && c >= N_NODES) c -= N_NODES;
                    raw[k] = *(const ushort4*)(gsrc + (size_t)c * N_HID + s * 4);
                }
#pragma unroll
                for (int k = 0; k < 8; ++k) {
                    float v = __uint_as_float((unsigned)(p[k] >> 32));
                    acc.x = fmaf(v, bf_to_f(raw[k].x), acc.x);
                    acc.y = fmaf(v, bf_to_f(raw[k].y), acc.y);
                    acc.z = fmaf(v, bf_to_f(raw[k].z), acc.z);
                    acc.w = fmaf(v, bf_to_f(raw[k].w), acc.w);
                }
            }
        } else {
            int e0 = eB[i];
            for (int j = sB[i]; j < e0; j += 8) {
                int last = e0 - 1;
                ull p[8];
#pragma unroll
                for (int k = 0; k < 8; ++k) p[k] = pairs[min(j + k, last)];
                ushort4 raw[8];
#pragma unroll
                for (int k = 0; k < 8; ++k) {
                    unsigned c = (unsigned)p[k] & 0x7FFFFu;
                    if (LAYER == 1 && c >= N_NODES) c -= N_NODES;
                    raw[k] = *(const ushort4*)(gsrc + (size_t)c * N_HID + s * 4);
                }
#pragma unroll
                for (int k = 0; k < 8; ++k) {
                    float v = (j + k < e0) ? __uint_as_float((unsigned)(p[k] >> 32)) : 0.f;
                    acc.x = fmaf(v, bf_to_f(raw[k].x), acc.x);
                    acc.y = fmaf(v, bf_to_f(raw[k].y), acc.y);
                    acc.z = fmaf(v, bf_to_f(raw[k].z), acc.z);
                    acc.w = fmaf(v, bf_to_f(raw[k].w), acc.w);
                }
            }
        }
        uint2 pk;
        pk.x = pack_bf2(acc.x, acc.y);
        pk.y = pack_bf2(acc.z, acc.w);
        *(uint2*)&agg[w][i * 4 + g][s * 4] = pk;
    }
    asm volatile("s_waitcnt lgkmcnt(0)" ::: "memory");
    __builtin_amdgcn_sched_barrier(0);

    // ---- MFMA: z(16x64) = agg(16x64) @ W(64x64) ----
    short8v a0 = *(const short8v*)&agg[w][s][g * 8];
    short8v a1 = *(const short8v*)&agg[w][s][32 + g * 8];
    f32x4 c[4];
    const f32x4 zero4 = {0.f, 0.f, 0.f, 0.f};
#pragma unroll
    for (int nt = 0; nt < 4; ++nt) {
        c[nt] = __builtin_amdgcn_mfma_f32_16x16x32_bf16(a0, bfrag[nt][0], zero4, 0, 0, 0);
        c[nt] = __builtin_amdgcn_mfma_f32_16x16x32_bf16(a1, bfrag[nt][1], c[nt], 0, 0, 0);
    }

    // ---- leaky + row l2norm (C/D: col = nt*16+s, row = g*4+r) ----
    float lv[4][4];
    float ss[4] = {0.f, 0.f, 0.f, 0.f};
#pragma unroll
    for (int nt = 0; nt < 4; ++nt)
#pragma unroll
        for (int r = 0; r < 4; ++r) {
            float z = c[nt][r];
            float l = (z >= 0.f) ? z : 0.5f * z;
            lv[nt][r] = l;
            ss[r] = fmaf(l, l, ss[r]);
        }
#pragma unroll
    for (int r = 0; r < 4; ++r) {
        float t = ss[r];
        t += __shfl_xor(t, 1, 64);
        t += __shfl_xor(t, 2, 64);
        t += __shfl_xor(t, 4, 64);
        t += __shfl_xor(t, 8, 64);
        ss[r] = 1.f / fmaxf(sqrtf(t), 1e-12f);
    }

    // ---- outputs ----
#pragma unroll
    for (int r = 0; r < 4; ++r) {
        int R = rbeg + w * 16 + g * 4 + r;
        if (LAYER == 1) {
            size_t eRow = isUI ? (size_t)R : (size_t)(R - N_NODES);
#pragma unroll
            for (int nt = 0; nt < 4; ++nt) {
                int col = nt * 16 + s;
                float eb = bf_to_f(embBf[eRow * N_HID + col]);
                tmp12out[(size_t)R * N_HID + col] = f_to_bf(fmaf(lv[nt][r], ss[r], eb));
                B2out[(size_t)R * N_HID + col]    = f_to_bf(lv[nt][r]);
            }
        } else {
            float* op = isUI ? out_ui + (size_t)R * N_HID
                             : out_s  + (size_t)(R - N_NODES) * N_HID;
#pragma unroll
            for (int nt = 0; nt < 4; ++nt) {
                int col = nt * 16 + s;
                float tb = bf_to_f(tmp12in[(size_t)R * N_HID + col]);
                op[col] = fmaf(lv[nt][r], ss[r], tb);
            }
        }
    }
}

// ===========================================================================
// Atomic fallback (only if ws too small for the sorted path)
// ===========================================================================
__global__ __launch_bounds__(256) void init_concat(const float* __restrict__ u,
                                                   const float* __restrict__ it,
                                                   float* __restrict__ A,
                                                   float* __restrict__ out) {
    int i = blockIdx.x * 256 + threadIdx.x;
    const int nu4 = N_USER * N_HID / 4;
    const int nt4 = N_NODES * N_HID / 4;
    if (i >= nt4) return;
    float4 v = (i < nu4) ? ((const float4*)u)[i] : ((const float4*)it)[i - nu4];
    ((float4*)A)[i]   = v;
    ((float4*)out)[i] = v;
}

__global__ __launch_bounds__(256) void copy2(const float* __restrict__ src,
                                             float* __restrict__ d0,
                                             float* __restrict__ d1, int n4) {
    int i = blockIdx.x * 256 + threadIdx.x;
    if (i >= n4) return;
    float4 v = ((const float4*)src)[i];
    ((float4*)d0)[i] = v;
    ((float4*)d1)[i] = v;
}

__global__ __launch_bounds__(256) void gemm64(const float* __restrict__ X,
                                              const float* __restrict__ W,
                                              float* __restrict__ Y, int nrows) {
    __shared__ float Ws[N_HID * N_HID];
    int tid = threadIdx.x;
#pragma unroll
    for (int c = 0; c < 16; ++c) Ws[c * 256 + tid] = W[c * 256 + tid];
    __syncthreads();
    int row = blockIdx.x * 256 + tid;
    if (row >= nrows) return;
    float x[N_HID];
    const float4* xr = (const float4*)(X + (size_t)row * N_HID);
#pragma unroll
    for (int c = 0; c < 16; ++c) {
        float4 v = xr[c];
        x[4*c+0] = v.x; x[4*c+1] = v.y; x[4*c+2] = v.z; x[4*c+3] = v.w;
    }
    float4* y4 = (float4*)(Y + (size_t)row * N_HID);
    for (int jc = 0; jc < 16; ++jc) {
        float4 a = make_float4(0.f,0.f,0.f,0.f);
#pragma unroll
        for (int k = 0; k < N_HID; ++k) {
            float4 wv = *((const float4*)&Ws[k * N_HID + jc * 4]);
            a.x += x[k]*wv.x; a.y += x[k]*wv.y; a.z += x[k]*wv.z; a.w += x[k]*wv.w;
        }
        y4[jc] = a;
    }
}

__global__ __launch_bounds__(256) void spmm_scatter(const int* __restrict__ rows,
                                                    const int* __restrict__ cols,
                                                    const float* __restrict__ vals,
                                                    const float* __restrict__ X,
                                                    float* __restrict__ Y, int nedges) {
    long long t = (long long)blockIdx.x * 256 + threadIdx.x;
    int e = (int)(t >> 6);
    int h = (int)(t & 63);
    if (e >= nedges) return;
    atomicAdd(&Y[rows[e] * N_HID + h], vals[e] * X[cols[e] * N_HID + h]);
}

__global__ __launch_bounds__(256) void leaky_norm_acc(float* __restrict__ Y,
                                                      float* __restrict__ out, int nrows) {
    int row = blockIdx.x * 4 + (threadIdx.x >> 6);
    int h   = threadIdx.x & 63;
    if (row >= nrows) return;
    int idx = row * N_HID + h;
    float v = Y[idx];
    v = (v >= 0.f) ? v : 0.5f * v;
    Y[idx] = v;
    float s = v * v;
#pragma unroll
    for (int off = 32; off > 0; off >>= 1) s += __shfl_xor(s, off, 64);
    out[idx] += v / fmaxf(sqrtf(s), 1e-12f);
}

// ===========================================================================
extern "C" void kernel_launch(void* const* d_in, const int* in_sizes, int n_in,
                              void* d_out, int out_size, void* d_ws, size_t ws_size,
                              hipStream_t stream) {
    const float* user_emb = (const float*)d_in[0];
    const float* item_emb = (const float*)d_in[1];
    const float* ui_w     = (const float*)d_in[2];
    const float* s_w      = (const float*)d_in[3];
    const int*   ui_rows  = (const int*)d_in[4];
    const int*   ui_cols  = (const int*)d_in[5];
    const float* ui_vals  = (const float*)d_in[6];
    const int*   s_rows   = (const int*)d_in[7];
    const int*   s_cols   = (const int*)d_in[8];
    const float* s_vals   = (const float*)d_in[9];

    float* out_ui = (float*)d_out;
    float* out_s  = (float*)d_out + (size_t)N_NODES * N_HID;

    const size_t szUI  = (size_t)N_NODES * N_HID * sizeof(float);     // 64.0 MB
    const size_t szEB  = (size_t)N_NODES * N_HID * sizeof(short);     // 32.0 MB
    const size_t szBF  = (size_t)N_TOT   * N_HID * sizeof(short);     // 44.8 MB
    const size_t rsPad = 1400832;                                     // (N_TOT+1)*4 pad
    const size_t lsSz  = (size_t)NBBIN * LSTR * 4 + 4096;             // ~341 KB

    const int uiBlocks = (N_NODES + BR - 1) / BR;    // 3907
    const int sBlocks  = (N_USER  + BR - 1) / BR;    // 1563
    const int nbScan   = (N_TOT + 1 + 511) / 512;    // 684
    const int nbEC     = (N_NODES * N_HID / 8 + 255) / 256;

    const size_t pairsCapPad = ((size_t)E_TOT + 7ull * N_TOT) * 8;    // 35.6 MB
    const size_t pairsCapStd = (size_t)E_TOT * 8;                     // 16.0 MB

    const size_t needPad = szEB + 2 * szBF + pairsCapPad + rsPad + 8192 + lsSz;
    const size_t needStd = szEB + 2 * szBF + pairsCapStd + rsPad + 8192 + lsSz;

    if (ws_size >= needStd) {
        const bool padded = (ws_size >= needPad);
        const size_t pairsCap = padded ? pairsCapPad : pairsCapStd;

        unsigned short* embBf = (unsigned short*)d_ws;
        unsigned short* B2    = (unsigned short*)((char*)d_ws + szEB);
        unsigned short* tmp12 = (unsigned short*)((char*)d_ws + szEB + szBF);
        char* p = (char*)d_ws + szEB + 2 * szBF;
        ull* pairs     = (ull*)p;            p += pairsCap;
        int* rowStart  = (int*)p;            p += rsPad;
        int* blockSums = (int*)p;            p += 8192;
        int* lstartAll = (int*)p;
        ull* pairsA    = (ull*)tmp12;        // staging aliases tmp12 (16.1MB ≤ 44.8)

        // ---- prepass + sort ----
        embcast<<<nbEC, 256, 0, stream>>>(user_emb, item_emb, embBf);
        hipMemsetAsync(rowStart, 0, (size_t)(N_TOT + 1) * 4, stream);
        bin_local<<<NBBIN, 512, 0, stream>>>(ui_rows, ui_cols, ui_vals,
                                             s_rows, s_cols, s_vals,
                                             rowStart, pairsA, lstartAll);
        scan_block512<<<nbScan, 256, 0, stream>>>(rowStart, blockSums,
                                                  N_TOT + 1, padded ? 1 : 0);
        scan_sums<<<1, 1024, 0, stream>>>(blockSums, nbScan);
        scan_add512<<<nbScan, 256, 0, stream>>>(rowStart, blockSums, N_TOT + 1);
        fine_gather<<<NBKT, 512, 0, stream>>>(pairsA, lstartAll, rowStart, pairs,
                                              padded ? 1 : 0);

        // ---- 2 fused spmm dispatches (MFMA epilogue) ----
        const int grid = uiBlocks + sBlocks;
        const float* Wui2 = ui_w + N_HID * N_HID;
        const float* Ws2  = s_w  + N_HID * N_HID;
        if (padded) {
            spmm_m<1, true><<<grid, 256, 0, stream>>>(pairs, rowStart, embBf,
                                                      nullptr, B2, nullptr, tmp12,
                                                      ui_w, s_w, out_ui, out_s, uiBlocks);
            spmm_m<2, true><<<grid, 256, 0, stream>>>(pairs, rowStart, embBf,
                                                      B2, nullptr, tmp12, nullptr,
                                                      Wui2, Ws2, out_ui, out_s, uiBlocks);
        } else {
            spmm_m<1, false><<<grid, 256, 0, stream>>>(pairs, rowStart, embBf,
                                                       nullptr, B2, nullptr, tmp12,
                                                       ui_w, s_w, out_ui, out_s, uiBlocks);
            spmm_m<2, false><<<grid, 256, 0, stream>>>(pairs, rowStart, embBf,
                                                       B2, nullptr, tmp12, nullptr,
                                                       Wui2, Ws2, out_ui, out_s, uiBlocks);
        }
        return;
    }

    // ------------------- fallback: atomic path -------------------
    float* A = (float*)d_ws;
    float* B = (float*)((char*)d_ws + szUI);
    init_concat<<<(N_NODES * N_HID / 4 + 255) / 256, 256, 0, stream>>>(
        user_emb, item_emb, A, out_ui);
    for (int l = 0; l < 2; ++l) {
        gemm64<<<(N_NODES + 255) / 256, 256, 0, stream>>>(
            A, ui_w + l * N_HID * N_HID, B, N_NODES);
        hipMemsetAsync(A, 0, szUI, stream);
        spmm_scatter<<<(int)(((long long)E_UI * 64) / 256), 256, 0, stream>>>(
            ui_rows, ui_cols, ui_vals, B, A, E_UI);
        leaky_norm_acc<<<(N_NODES + 3) / 4, 256, 0, stream>>>(A, out_ui, N_NODES);
    }
    copy2<<<(N_USER * N_HID / 4 + 255) / 256, 256, 0, stream>>>(
        user_emb, A, out_s, N_USER * N_HID / 4);
    const size_t sBytes = (size_t)N_USER * N_HID * sizeof(float);
    for (int l = 0; l < 2; ++l) {
        gemm64<<<(N_USER + 255) / 256, 256, 0, stream>>>(
            A, s_w + l * N_HID * N_HID, B, N_USER);
        hipMemsetAsync(A, 0, sBytes, stream);
        spmm_scatter<<<(int)(((long long)E_S * 64) / 256), 256, 0, stream>>>(
            s_rows, s_cols, s_vals, B, A, E_S);
        leaky_norm_acc<<<(N_USER + 3) / 4, 256, 0, stream>>>(A, out_s, N_USER);
    }
}

// Round 14
// 234.837 us; speedup vs baseline: 1.3504x; 1.3186x over previous
//
#include <hip/hip_runtime.h>

#define N_USER   100000
#define N_ITEM   150000
#define N_NODES  250000
#define N_HID    64
#define E_UI     1000000
#define E_S      1000000
#define N_TOT    (N_NODES + N_USER)      // 350000
#define E_TOT    (E_UI + E_S)            // 2000000

#define BR     64                         // rows per block (spmm)
#define CH     4096                       // edges per binning chunk
#define NBBIN  ((E_TOT + CH - 1) / CH)    // 489
#define RPB    1024                       // rows per coarse bucket
#define RPB_SH 10
#define NBKT   ((N_TOT + RPB - 1) / RPB)  // 342
#define NBKTP  512                        // padded bucket-array size
#define LSTR   344                        // lstartAll row stride (ints)
#define ASTR   72                         // agg LDS row stride (shorts, 144B)
#define BCAP_PAD 16384                    // per-bucket pairs capacity (padded)
#define BCAP_STD 12288                    // per-bucket pairs capacity (unpadded)

typedef unsigned long long ull;
typedef __attribute__((ext_vector_type(8))) short short8v;   // 8 bf16 (4 VGPR)
typedef __attribute__((ext_vector_type(4))) float f32x4;

__device__ __forceinline__ unsigned short f_to_bf(float f) {
    unsigned u = __float_as_uint(f);
    u += 0x7FFF + ((u >> 16) & 1);
    return (unsigned short)(u >> 16);
}
__device__ __forceinline__ float bf_to_f(unsigned short s) {
    return __uint_as_float((unsigned)s << 16);
}
__device__ __forceinline__ unsigned pack_bf2(float a, float b) {
    return (unsigned)f_to_bf(a) | ((unsigned)f_to_bf(b) << 16);
}

// ===========================================================================
// prepass: bf16 cast of concat(user,item) -> embBf[250K][64]  (LDS-free)
// ===========================================================================
__global__ __launch_bounds__(256) void embcast(const float* __restrict__ u,
                                               const float* __restrict__ it,
                                               unsigned short* __restrict__ embBf) {
    int i = blockIdx.x * 256 + threadIdx.x;
    const int n8 = N_NODES * N_HID / 8;
    if (i >= n8) return;
    size_t base = (size_t)i * 8;
    const size_t nu = (size_t)N_USER * N_HID;
    const float* src = (base < nu) ? u + base : it + (base - nu);
    float4 a = *(const float4*)src;
    float4 b = *(const float4*)(src + 4);
    uint4 o;
    o.x = pack_bf2(a.x, a.y); o.y = pack_bf2(a.z, a.w);
    o.z = pack_bf2(b.x, b.y); o.w = pack_bf2(b.z, b.w);
    *(uint4*)&embBf[base] = o;
}

// ===========================================================================
// bin_local: per-block private bucket-grouping. ZERO global atomics.
//   phase 1: bucket histogram (LDS)
//   scan:    512-wide exclusive prefix -> lstart -> lstartAll (+sentinel)
//   phase 2: re-read edges, place grouped into private region pairsA[blk*CH+..]
//   entry = v<<32 | rLow<<19 | c
// ===========================================================================
__global__ __launch_bounds__(512) void bin_local(const int* __restrict__ ui_rows,
                                                 const int* __restrict__ ui_cols,
                                                 const float* __restrict__ ui_vals,
                                                 const int* __restrict__ s_rows,
                                                 const int* __restrict__ s_cols,
                                                 const float* __restrict__ s_vals,
                                                 ull* __restrict__ pairsA,
                                                 int* __restrict__ lstartAll) {
    __shared__ int hist[NBKTP];
    __shared__ int lstart[NBKTP];
    __shared__ int cnt2[NBKTP];
    const int t = threadIdx.x;
    hist[t] = 0; cnt2[t] = 0;
    __syncthreads();

    const int e0 = blockIdx.x * CH;
    const int n  = min(CH, E_TOT - e0);

    // phase 1: bucket histogram (LDS atomics only)
    for (int i = t; i < n; i += 512) {
        int g = e0 + i, r;
        if (g < E_UI) r = ui_rows[g];
        else          r = N_NODES + s_rows[g - E_UI];
        atomicAdd(&hist[r >> RPB_SH], 1);
    }
    __syncthreads();

    // 512-wide exclusive scan (1 elem/thread)
    int v = hist[t];
    lstart[t] = v;
    __syncthreads();
    for (int off = 1; off < NBKTP; off <<= 1) {
        int a = (t >= off) ? lstart[t - off] : 0;
        __syncthreads();
        lstart[t] += a;
        __syncthreads();
    }
    int ex = lstart[t] - v;
    __syncthreads();
    lstart[t] = ex;
    if (t <= NBKT) lstartAll[blockIdx.x * LSTR + t] = ex;   // [NBKT] = n
    __syncthreads();

    // phase 2: re-read + place grouped into private region
    for (int i = t; i < n; i += 512) {
        int g = e0 + i, r, c; float val;
        if (g < E_UI) { r = ui_rows[g];            c = ui_cols[g];            val = ui_vals[g]; }
        else          { int k = g - E_UI;
                        r = N_NODES + s_rows[k];   c = N_NODES + s_cols[k];   val = s_vals[k]; }
        int b = r >> RPB_SH;
        ull entry = ((ull)__float_as_uint(val) << 32) |
                    ((ull)(unsigned)(r & (RPB - 1)) << 19) | (unsigned)c;
        int l = atomicAdd(&cnt2[b], 1);
        pairsA[(size_t)blockIdx.x * CH + lstart[b] + l] = entry;
    }
}

// ===========================================================================
// fine_gather2: one block per bucket. NO global atomics, NO global scan.
//   pass A: per-row count into LDS
//   scan:   1024-wide (padded) prefix -> rowStart[r0..] = b*BCAP + prefix
//   pass B: re-read segments, scatter to exact CSR slot via LDS cursors
//   padfill pad slots; bucketEnd[b] = padded data end (spmm clamps the
//   bucket-boundary row with it); last bucket writes rowStart[N_TOT].
// ===========================================================================
template <bool PAD>
__global__ __launch_bounds__(512) void fine_gather2(const ull* __restrict__ pairsA,
                                                    const int* __restrict__ lstartAll,
                                                    int* __restrict__ rowStart,
                                                    int* __restrict__ bucketEnd,
                                                    ull* __restrict__ pairs,
                                                    int bcap) {
    __shared__ int cur[RPB];       // counts -> absolute cursor starts
    __shared__ int sc[RPB];        // scan workspace -> pad-end
    const int b = blockIdx.x, t = threadIdx.x;
    const int r0 = b * RPB;
    const int nr = min(RPB, N_TOT - r0);
    const int base = b * bcap;

    cur[t] = 0; cur[t + 512] = 0;
    __syncthreads();

    const int q    = t >> 4;        // 32 quarters
    const int lane = t & 15;

    // pass A: per-row counts
    for (int blk = q; blk < NBBIN; blk += 32) {
        int s = lstartAll[blk * LSTR + b];
        int e = lstartAll[blk * LSTR + b + 1];
        const ull* src = pairsA + (size_t)blk * CH;
        for (int j = s + lane; j < e; j += 16)
            atomicAdd(&cur[(int)((src[j] >> 19) & (RPB - 1))], 1);
    }
    __syncthreads();

    // padded scan over 1024 counts (2 elems/thread, Hillis–Steele inclusive)
    int c0 = cur[t], c1 = cur[t + 512];
    int p0 = PAD ? ((c0 + 7) & ~7) : c0;
    int p1 = PAD ? ((c1 + 7) & ~7) : c1;
    sc[t] = p0; sc[t + 512] = p1;
    __syncthreads();
    for (int off = 1; off < RPB; off <<= 1) {
        int a = (t >= off) ? sc[t - off] : 0;
        int bb = (t + 512 >= off) ? sc[t + 512 - off] : 0;
        __syncthreads();
        sc[t] += a; sc[t + 512] += bb;
        __syncthreads();
    }
    int inc0 = sc[t], inc1 = sc[t + 512];
    __syncthreads();
    int st0 = base + inc0 - p0;
    int st1 = base + inc1 - p1;
    cur[t] = st0;            cur[t + 512] = st1;            // cursor starts
    sc[t]  = st0 + p0;       sc[t + 512]  = st1 + p1;       // pad-ends
    if (t < nr)        rowStart[r0 + t] = st0;
    if (t + 512 < nr)  rowStart[r0 + t + 512] = st1;
    if (t == 511) {
        bucketEnd[b] = st1 + p1;                           // bucket data end
        if (b == NBKT - 1) rowStart[N_TOT] = st1 + p1;     // global sentinel
    }
    __syncthreads();

    // pass B: scatter (segments are L2-hot from pass A)
    for (int blk = q; blk < NBBIN; blk += 32) {
        int s = lstartAll[blk * LSTR + b];
        int e = lstartAll[blk * LSTR + b + 1];
        const ull* src = pairsA + (size_t)blk * CH;
        for (int j = s + lane; j < e; j += 16) {
            ull en = src[j];
            int rLow = (int)((en >> 19) & (RPB - 1));
            int pos = atomicAdd(&cur[rLow], 1);
            pairs[pos] = (en & 0xFFFFFFFF00000000ull) | (en & 0x7FFFFull);
        }
    }
    if (PAD) {
        __syncthreads();
        for (int i = t; i < nr; i += 512) {
            int end = sc[i];
            for (int j = cur[i]; j < end; ++j) pairs[j] = 0;   // v=0, c=0
        }
    }
}

// ===========================================================================
// spmm_m: quarter-wave gather (bf16 sources) + MFMA W-apply epilogue.
//   PADDED: rows are 8-aligned with zero-val pad entries -> mask-free loop.
//   Bucket-boundary rows clamp their end with bucketEnd (region gaps!).
//   LAYER 1: gather embBf; tmp12 = bf16(emb+n1); B2 = bf16(lv1)
//   LAYER 2: gather B2;    out = f32(tmp12) + n2
// ===========================================================================
template <int LAYER, bool PADDED>
__global__ __launch_bounds__(256) void spmm_m(const ull* __restrict__ pairs,
                                              const int* __restrict__ rowStart,
                                              const int* __restrict__ bucketEnd,
                                              const unsigned short* __restrict__ embBf,
                                              const unsigned short* __restrict__ B2in,
                                              unsigned short* __restrict__ B2out,
                                              const unsigned short* __restrict__ tmp12in,
                                              unsigned short* __restrict__ tmp12out,
                                              const float* __restrict__ Wui,
                                              const float* __restrict__ Wsoc,
                                              float* __restrict__ out_ui,
                                              float* __restrict__ out_s,
                                              int uiBlocks) {
    __shared__ unsigned short Wb[N_HID][ASTR];        // Wb[c][r] = bf16(W[r][c])
    __shared__ unsigned short agg[4][16][ASTR];
    const int tid = threadIdx.x;
    const bool isUI = (int)blockIdx.x < uiBlocks;
    const int bl    = isUI ? blockIdx.x : blockIdx.x - uiBlocks;
    const int rbeg  = isUI ? bl * BR : N_NODES + bl * BR;
    const int rlim  = isUI ? min(BR, N_NODES - bl * BR) : min(BR, N_USER - bl * BR);

    const float* W = isUI ? Wui : Wsoc;
    for (int idx = tid; idx < N_HID * N_HID; idx += 256) {
        int r = idx >> 6, c = idx & 63;
        Wb[c][r] = f_to_bf(W[idx]);
    }
    __syncthreads();

    const int w = tid >> 6;
    if (w * 16 >= rlim) return;             // rlim is always a multiple of 16
    const int s = tid & 15;
    const int g = (tid >> 4) & 3;

    short8v bfrag[4][2];
#pragma unroll
    for (int nt = 0; nt < 4; ++nt)
#pragma unroll
        for (int kt = 0; kt < 2; ++kt)
            bfrag[nt][kt] = *(const short8v*)&Wb[nt * 16 + s][kt * 32 + g * 8];

    const unsigned short* gsrc = (LAYER == 1) ? embBf : B2in;

    int sB[4], eB[4];
#pragma unroll
    for (int i = 0; i < 4; ++i) {
        int r = rbeg + w * 16 + i * 4 + g;
        sB[i] = rowStart[r];
        int e = rowStart[r + 1];
        if (((r + 1) & (RPB - 1)) == 0)     // last row of a bucket: region gap
            e = bucketEnd[r >> RPB_SH];
        eB[i] = e;
    }

    for (int i = 0; i < 4; ++i) {
        float4 acc = make_float4(0.f, 0.f, 0.f, 0.f);
        if (PADDED) {
            for (int j = sB[i]; j < eB[i]; j += 8) {   // mask-free: pads have v=0
                ull p[8];
#pragma unroll
                for (int k = 0; k < 8; ++k) p[k] = pairs[j + k];
                ushort4 raw[8];
#pragma unroll
                for (int k = 0; k < 8; ++k) {
                    unsigned c = (unsigned)p[k] & 0x7FFFFu;
                    if (LAYER == 1 && c >= N_NODES) c -= N_NODES;
                    raw[k] = *(const ushort4*)(gsrc + (size_t)c * N_HID + s * 4);
                }
#pragma unroll
                for (int k = 0; k < 8; ++k) {
                    float v = __uint_as_float((unsigned)(p[k] >> 32));
                    acc.x = fmaf(v, bf_to_f(raw[k].x), acc.x);
                    acc.y = fmaf(v, bf_to_f(raw[k].y), acc.y);
                    acc.z = fmaf(v, bf_to_f(raw[k].z), acc.z);
                    acc.w = fmaf(v, bf_to_f(raw[k].w), acc.w);
                }
            }
        } else {
            int e0 = eB[i];
            for (int j = sB[i]; j < e0; j += 8) {
                int last = e0 - 1;
                ull p[8];
#pragma unroll
                for (int k = 0; k < 8; ++k) p[k] = pairs[min(j + k, last)];
                ushort4 raw[8];
#pragma unroll
                for (int k = 0; k < 8; ++k) {
                    unsigned c = (unsigned)p[k] & 0x7FFFFu;
                    if (LAYER == 1 && c >= N_NODES) c -= N_NODES;
                    raw[k] = *(const ushort4*)(gsrc + (size_t)c * N_HID + s * 4);
                }
#pragma unroll
                for (int k = 0; k < 8; ++k) {
                    float v = (j + k < e0) ? __uint_as_float((unsigned)(p[k] >> 32)) : 0.f;
                    acc.x = fmaf(v, bf_to_f(raw[k].x), acc.x);
                    acc.y = fmaf(v, bf_to_f(raw[k].y), acc.y);
                    acc.z = fmaf(v, bf_to_f(raw[k].z), acc.z);
                    acc.w = fmaf(v, bf_to_f(raw[k].w), acc.w);
                }
            }
        }
        uint2 pk;
        pk.x = pack_bf2(acc.x, acc.y);
        pk.y = pack_bf2(acc.z, acc.w);
        *(uint2*)&agg[w][i * 4 + g][s * 4] = pk;
    }
    asm volatile("s_waitcnt lgkmcnt(0)" ::: "memory");
    __builtin_amdgcn_sched_barrier(0);

    // ---- MFMA: z(16x64) = agg(16x64) @ W(64x64) ----
    short8v a0 = *(const short8v*)&agg[w][s][g * 8];
    short8v a1 = *(const short8v*)&agg[w][s][32 + g * 8];
    f32x4 c[4];
    const f32x4 zero4 = {0.f, 0.f, 0.f, 0.f};
#pragma unroll
    for (int nt = 0; nt < 4; ++nt) {
        c[nt] = __builtin_amdgcn_mfma_f32_16x16x32_bf16(a0, bfrag[nt][0], zero4, 0, 0, 0);
        c[nt] = __builtin_amdgcn_mfma_f32_16x16x32_bf16(a1, bfrag[nt][1], c[nt], 0, 0, 0);
    }

    // ---- leaky + row l2norm (C/D: col = nt*16+s, row = g*4+r) ----
    float lv[4][4];
    float ss[4] = {0.f, 0.f, 0.f, 0.f};
#pragma unroll
    for (int nt = 0; nt < 4; ++nt)
#pragma unroll
        for (int r = 0; r < 4; ++r) {
            float z = c[nt][r];
            float l = (z >= 0.f) ? z : 0.5f * z;
            lv[nt][r] = l;
            ss[r] = fmaf(l, l, ss[r]);
        }
#pragma unroll
    for (int r = 0; r < 4; ++r) {
        float t = ss[r];
        t += __shfl_xor(t, 1, 64);
        t += __shfl_xor(t, 2, 64);
        t += __shfl_xor(t, 4, 64);
        t += __shfl_xor(t, 8, 64);
        ss[r] = 1.f / fmaxf(sqrtf(t), 1e-12f);
    }

    // ---- outputs ----
#pragma unroll
    for (int r = 0; r < 4; ++r) {
        int R = rbeg + w * 16 + g * 4 + r;
        if (LAYER == 1) {
            size_t eRow = isUI ? (size_t)R : (size_t)(R - N_NODES);
#pragma unroll
            for (int nt = 0; nt < 4; ++nt) {
                int col = nt * 16 + s;
                float eb = bf_to_f(embBf[eRow * N_HID + col]);
                tmp12out[(size_t)R * N_HID + col] = f_to_bf(fmaf(lv[nt][r], ss[r], eb));
                B2out[(size_t)R * N_HID + col]    = f_to_bf(lv[nt][r]);
            }
        } else {
            float* op = isUI ? out_ui + (size_t)R * N_HID
                             : out_s  + (size_t)(R - N_NODES) * N_HID;
#pragma unroll
            for (int nt = 0; nt < 4; ++nt) {
                int col = nt * 16 + s;
                float tb = bf_to_f(tmp12in[(size_t)R * N_HID + col]);
                op[col] = fmaf(lv[nt][r], ss[r], tb);
            }
        }
    }
}

// ===========================================================================
// Atomic fallback (only if ws too small for the sorted path)
// ===========================================================================
__global__ __launch_bounds__(256) void init_concat(const float* __restrict__ u,
                                                   const float* __restrict__ it,
                                                   float* __restrict__ A,
                                                   float* __restrict__ out) {
    int i = blockIdx.x * 256 + threadIdx.x;
    const int nu4 = N_USER * N_HID / 4;
    const int nt4 = N_NODES * N_HID / 4;
    if (i >= nt4) return;
    float4 v = (i < nu4) ? ((const float4*)u)[i] : ((const float4*)it)[i - nu4];
    ((float4*)A)[i]   = v;
    ((float4*)out)[i] = v;
}

__global__ __launch_bounds__(256) void copy2(const float* __restrict__ src,
                                             float* __restrict__ d0,
                                             float* __restrict__ d1, int n4) {
    int i = blockIdx.x * 256 + threadIdx.x;
    if (i >= n4) return;
    float4 v = ((const float4*)src)[i];
    ((float4*)d0)[i] = v;
    ((float4*)d1)[i] = v;
}

__global__ __launch_bounds__(256) void gemm64(const float* __restrict__ X,
                                              const float* __restrict__ W,
                                              float* __restrict__ Y, int nrows) {
    __shared__ float Ws[N_HID * N_HID];
    int tid = threadIdx.x;
#pragma unroll
    for (int c = 0; c < 16; ++c) Ws[c * 256 + tid] = W[c * 256 + tid];
    __syncthreads();
    int row = blockIdx.x * 256 + tid;
    if (row >= nrows) return;
    float x[N_HID];
    const float4* xr = (const float4*)(X + (size_t)row * N_HID);
#pragma unroll
    for (int c = 0; c < 16; ++c) {
        float4 v = xr[c];
        x[4*c+0] = v.x; x[4*c+1] = v.y; x[4*c+2] = v.z; x[4*c+3] = v.w;
    }
    float4* y4 = (float4*)(Y + (size_t)row * N_HID);
    for (int jc = 0; jc < 16; ++jc) {
        float4 a = make_float4(0.f,0.f,0.f,0.f);
#pragma unroll
        for (int k = 0; k < N_HID; ++k) {
            float4 wv = *((const float4*)&Ws[k * N_HID + jc * 4]);
            a.x += x[k]*wv.x; a.y += x[k]*wv.y; a.z += x[k]*wv.z; a.w += x[k]*wv.w;
        }
        y4[jc] = a;
    }
}

__global__ __launch_bounds__(256) void spmm_scatter(const int* __restrict__ rows,
                                                    const int* __restrict__ cols,
                                                    const float* __restrict__ vals,
                                                    const float* __restrict__ X,
                                                    float* __restrict__ Y, int nedges) {
    long long t = (long long)blockIdx.x * 256 + threadIdx.x;
    int e = (int)(t >> 6);
    int h = (int)(t & 63);
    if (e >= nedges) return;
    atomicAdd(&Y[rows[e] * N_HID + h], vals[e] * X[cols[e] * N_HID + h]);
}

__global__ __launch_bounds__(256) void leaky_norm_acc(float* __restrict__ Y,
                                                      float* __restrict__ out, int nrows) {
    int row = blockIdx.x * 4 + (threadIdx.x >> 6);
    int h   = threadIdx.x & 63;
    if (row >= nrows) return;
    int idx = row * N_HID + h;
    float v = Y[idx];
    v = (v >= 0.f) ? v : 0.5f * v;
    Y[idx] = v;
    float s = v * v;
#pragma unroll
    for (int off = 32; off > 0; off >>= 1) s += __shfl_xor(s, off, 64);
    out[idx] += v / fmaxf(sqrtf(s), 1e-12f);
}

// ===========================================================================
extern "C" void kernel_launch(void* const* d_in, const int* in_sizes, int n_in,
                              void* d_out, int out_size, void* d_ws, size_t ws_size,
                              hipStream_t stream) {
    const float* user_emb = (const float*)d_in[0];
    const float* item_emb = (const float*)d_in[1];
    const float* ui_w     = (const float*)d_in[2];
    const float* s_w      = (const float*)d_in[3];
    const int*   ui_rows  = (const int*)d_in[4];
    const int*   ui_cols  = (const int*)d_in[5];
    const float* ui_vals  = (const float*)d_in[6];
    const int*   s_rows   = (const int*)d_in[7];
    const int*   s_cols   = (const int*)d_in[8];
    const float* s_vals   = (const float*)d_in[9];

    float* out_ui = (float*)d_out;
    float* out_s  = (float*)d_out + (size_t)N_NODES * N_HID;

    const size_t szUI  = (size_t)N_NODES * N_HID * sizeof(float);     // 64.0 MB
    const size_t szEB  = (size_t)N_NODES * N_HID * sizeof(short);     // 32.0 MB
    const size_t szBF  = (size_t)N_TOT   * N_HID * sizeof(short);     // 44.8 MB
    const size_t rsPad = 1400832;                                     // (N_TOT+1)*4 pad
    const size_t lsSz  = 1 << 20;                                     // lstartAll+bucketEnd

    const int uiBlocks = (N_NODES + BR - 1) / BR;    // 3907
    const int sBlocks  = (N_USER  + BR - 1) / BR;    // 1563
    const int nbEC     = (N_NODES * N_HID / 8 + 255) / 256;

    const size_t pairsCapPad = (size_t)NBKT * BCAP_PAD * 8;   // 44.8 MB
    const size_t pairsCapStd = (size_t)NBKT * BCAP_STD * 8;   // 33.6 MB

    const size_t needPad = szEB + 2 * szBF + pairsCapPad + rsPad + lsSz;  // ~168 MB
    const size_t needStd = szEB + 2 * szBF + pairsCapStd + rsPad + lsSz;  // ~157 MB

    if (ws_size >= needStd) {
        const bool padded = (ws_size >= needPad);
        const int  bcap   = padded ? BCAP_PAD : BCAP_STD;
        const size_t pairsCap = padded ? pairsCapPad : pairsCapStd;

        unsigned short* embBf = (unsigned short*)d_ws;
        unsigned short* B2    = (unsigned short*)((char*)d_ws + szEB);
        unsigned short* tmp12 = (unsigned short*)((char*)d_ws + szEB + szBF);
        char* p = (char*)d_ws + szEB + 2 * szBF;
        ull* pairs     = (ull*)p;            p += pairsCap;
        int* rowStart  = (int*)p;            p += rsPad;
        int* lstartAll = (int*)p;
        int* bucketEnd = lstartAll + (size_t)NBBIN * LSTR;
        ull* pairsA    = (ull*)tmp12;        // staging aliases tmp12 (16MB ≤ 44.8)

        // ---- prepass + sort (3 dispatches, zero global atomics) ----
        embcast<<<nbEC, 256, 0, stream>>>(user_emb, item_emb, embBf);
        bin_local<<<NBBIN, 512, 0, stream>>>(ui_rows, ui_cols, ui_vals,
                                             s_rows, s_cols, s_vals,
                                             pairsA, lstartAll);
        if (padded)
            fine_gather2<true><<<NBKT, 512, 0, stream>>>(pairsA, lstartAll,
                                                         rowStart, bucketEnd,
                                                         pairs, bcap);
        else
            fine_gather2<false><<<NBKT, 512, 0, stream>>>(pairsA, lstartAll,
                                                          rowStart, bucketEnd,
                                                          pairs, bcap);

        // ---- 2 fused spmm dispatches (MFMA epilogue) ----
        const int grid = uiBlocks + sBlocks;
        const float* Wui2 = ui_w + N_HID * N_HID;
        const float* Ws2  = s_w  + N_HID * N_HID;
        if (padded) {
            spmm_m<1, true><<<grid, 256, 0, stream>>>(pairs, rowStart, bucketEnd, embBf,
                                                      nullptr, B2, nullptr, tmp12,
                                                      ui_w, s_w, out_ui, out_s, uiBlocks);
            spmm_m<2, true><<<grid, 256, 0, stream>>>(pairs, rowStart, bucketEnd, embBf,
                                                      B2, nullptr, tmp12, nullptr,
                                                      Wui2, Ws2, out_ui, out_s, uiBlocks);
        } else {
            spmm_m<1, false><<<grid, 256, 0, stream>>>(pairs, rowStart, bucketEnd, embBf,
                                                       nullptr, B2, nullptr, tmp12,
                                                       ui_w, s_w, out_ui, out_s, uiBlocks);
            spmm_m<2, false><<<grid, 256, 0, stream>>>(pairs, rowStart, bucketEnd, embBf,
                                                       B2, nullptr, tmp12, nullptr,
                                                       Wui2, Ws2, out_ui, out_s, uiBlocks);
        }
        return;
    }

    // ------------------- fallback: atomic path -------------------
    float* A = (float*)d_ws;
    float* B = (float*)((char*)d_ws + szUI);
    init_concat<<<(N_NODES * N_HID / 4 + 255) / 256, 256, 0, stream>>>(
        user_emb, item_emb, A, out_ui);
    for (int l = 0; l < 2; ++l) {
        gemm64<<<(N_NODES + 255) / 256, 256, 0, stream>>>(
            A, ui_w + l * N_HID * N_HID, B, N_NODES);
        hipMemsetAsync(A, 0, szUI, stream);
        spmm_scatter<<<(int)(((long long)E_UI * 64) / 256), 256, 0, stream>>>(
            ui_rows, ui_cols, ui_vals, B, A, E_UI);
        leaky_norm_acc<<<(N_NODES + 3) / 4, 256, 0, stream>>>(A, out_ui, N_NODES);
    }
    copy2<<<(N_USER * N_HID / 4 + 255) / 256, 256, 0, stream>>>(
        user_emb, A, out_s, N_USER * N_HID / 4);
    const size_t sBytes = (size_t)N_USER * N_HID * sizeof(float);
    for (int l = 0; l < 2; ++l) {
        gemm64<<<(N_USER + 255) / 256, 256, 0, stream>>>(
            A, s_w + l * N_HID * N_HID, B, N_USER);
        hipMemsetAsync(A, 0, sBytes, stream);
        spmm_scatter<<<(int)(((long long)E_S * 64) / 256), 256, 0, stream>>>(
            s_rows, s_cols, s_vals, B, A, E_S);
        leaky_norm_acc<<<(N_USER + 3) / 4, 256, 0, stream>>>(A, out_s, N_USER);
    }
}